// Round 1
// baseline (2998.438 us; speedup 1.0000x reference)
//
#include <hip/hip_runtime.h>
#include <cstdint>
#include <cstddef>

typedef __bf16 bf16;
typedef float f32x4 __attribute__((ext_vector_type(4)));
typedef bf16 bf16x8 __attribute__((ext_vector_type(8)));
typedef bf16 bf16x4 __attribute__((ext_vector_type(4)));

#define DM    4096
#define LL    2048
#define BB    2
#define BT    4096      /* B*L */
#define II    4096
#define GN_   1024
#define CONVD 6144
#define PROJD 10304
#define NPAD  10368     /* PROJ padded to multiple of 128 */
#define HH    64
#define PP    64
#define NN    128

/* ---- output layout (floats) ---- */
#define OUT_OFS_CONV  16777216   /* 4096*4096 */
#define OUT_OFS_STATE 16814080   /* + 2*6144*3 */

/* ---- workspace layout (bytes) ---- */
#define WS_HSB    0UL                   /* bf16 4096x4096      33554432 */
#define WS_WINB   33554432UL            /* bf16 10368x4096     84934656 */
#define WS_PROJ   118489088UL           /* f32  4096x10368    169869312 */
#define WS_XBC    288358400UL           /* f32  4096x6144     100663296 */
#define WS_DTP    389021696UL           /* f32  4096x64         1048576 */
#define WS_DA     390070272UL           /* f32  4096x64         1048576 */
#define WS_Y      391118848UL           /* f32  4096x4096      67108864 */
#define WS_YNB    458227712UL           /* bf16 4096x4096      33554432 */
#define WS_WOUTB  491782144UL           /* bf16 4096x4096      33554432 */

__device__ __forceinline__ void gl2lds16(const void* g, void* l) {
  __builtin_amdgcn_global_load_lds(
      (__attribute__((address_space(1))) unsigned int*)(uintptr_t)g,
      (__attribute__((address_space(3))) unsigned int*)(uintptr_t)l, 16, 0, 0);
}
__device__ __forceinline__ void gl2lds4(const void* g, void* l) {
  __builtin_amdgcn_global_load_lds(
      (__attribute__((address_space(1))) unsigned int*)(uintptr_t)g,
      (__attribute__((address_space(3))) unsigned int*)(uintptr_t)l, 4, 0, 0);
}

/* ---------------- cast fp32 -> bf16 (with zero-pad tail) ---------------- */
__global__ __launch_bounds__(256) void cast_kernel(const float* __restrict__ src,
                                                   bf16* __restrict__ dst,
                                                   long nsrc, long ndst) {
  long i = ((long)blockIdx.x * 256 + threadIdx.x) * 4;
  if (i >= ndst) return;
  bf16x4 o;
  if (i < nsrc) {
    float4 v = *(const float4*)(src + i);
    o[0] = (bf16)v.x; o[1] = (bf16)v.y; o[2] = (bf16)v.z; o[3] = (bf16)v.w;
  } else {
    o[0] = (bf16)0.f; o[1] = (bf16)0.f; o[2] = (bf16)0.f; o[3] = (bf16)0.f;
  }
  *(bf16x4*)(dst + i) = o;
}

/* ---------------- bf16 MFMA GEMM, C[M,N] = A[M,K] * B[N,K]^T ------------ */
/* grid: (N/128, M/128), block 256.  m97-style: global_load_lds staging.    */
__global__ __launch_bounds__(256, 3) void gemm_bt(const bf16* __restrict__ A,
                                                  const bf16* __restrict__ B,
                                                  float* __restrict__ C,
                                                  int M, int N, int K) {
  const int nb = blockIdx.x, mb = blockIdx.y;
  const int tid  = threadIdx.x;
  const int wave = tid >> 6, lane = tid & 63;
  const int wm = wave >> 1, wn = wave & 1;
  const int l16 = lane & 15, quad = lane >> 4;

  __shared__ __align__(16) bf16 As[128][32];
  __shared__ __align__(16) bf16 Bs[128][32];

  /* staging: chunk c = wave*2+q covers rows c*16..c*16+15 (1024B each)     */
  const int r0 = lane >> 2;          /* row within chunk  */
  const int kc = (lane & 3) * 8;     /* k offset in elems */
  const int c0 = wave * 2, c1 = wave * 2 + 1;
  const bf16* pA0 = A + (size_t)(mb * 128 + c0 * 16 + r0) * K + kc;
  const bf16* pA1 = A + (size_t)(mb * 128 + c1 * 16 + r0) * K + kc;
  const bf16* pB0 = B + (size_t)(nb * 128 + c0 * 16 + r0) * K + kc;
  const bf16* pB1 = B + (size_t)(nb * 128 + c1 * 16 + r0) * K + kc;
  bf16* lA0 = &As[c0 * 16][0]; bf16* lA1 = &As[c1 * 16][0];
  bf16* lB0 = &Bs[c0 * 16][0]; bf16* lB1 = &Bs[c1 * 16][0];

  f32x4 acc[4][4];
#pragma unroll
  for (int i = 0; i < 4; ++i)
#pragma unroll
    for (int j = 0; j < 4; ++j) acc[i][j] = (f32x4)0.f;

  for (int k0 = 0; k0 < K; k0 += 32) {
    gl2lds16(pA0, lA0); gl2lds16(pA1, lA1);
    gl2lds16(pB0, lB0); gl2lds16(pB1, lB1);
    pA0 += 32; pA1 += 32; pB0 += 32; pB1 += 32;
    __syncthreads();                        /* drains vmcnt -> tile ready */
    bf16x8 af[4], bfr[4];
#pragma unroll
    for (int mt = 0; mt < 4; ++mt)
      af[mt] = *(const bf16x8*)&As[wm * 64 + mt * 16 + l16][quad * 8];
#pragma unroll
    for (int nt = 0; nt < 4; ++nt)
      bfr[nt] = *(const bf16x8*)&Bs[wn * 64 + nt * 16 + l16][quad * 8];
#pragma unroll
    for (int mt = 0; mt < 4; ++mt)
#pragma unroll
      for (int nt = 0; nt < 4; ++nt)
        acc[mt][nt] = __builtin_amdgcn_mfma_f32_16x16x32_bf16(af[mt], bfr[nt], acc[mt][nt], 0, 0, 0);
    __syncthreads();                        /* protect LDS before next overwrite */
  }

#pragma unroll
  for (int mt = 0; mt < 4; ++mt) {
    const int row0 = mb * 128 + wm * 64 + mt * 16 + quad * 4;
#pragma unroll
    for (int nt = 0; nt < 4; ++nt) {
      const int col = nb * 128 + wn * 64 + nt * 16 + l16;
#pragma unroll
      for (int r = 0; r < 4; ++r)
        C[(size_t)(row0 + r) * N + col] = acc[mt][nt][r];
    }
  }
}

/* ---------------- conv(K=4) + SiLU over hbc slice ----------------------- */
__global__ __launch_bounds__(256) void conv_kernel(const float* __restrict__ proj,
                                                   const float* __restrict__ cw,
                                                   const float* __restrict__ cb,
                                                   float* __restrict__ xbc) {
  const int c  = blockIdx.x * 256 + threadIdx.x;  /* < 6144 */
  const int bt = blockIdx.y;                      /* < 4096 */
  const int t  = bt & (LL - 1);
  const float4 w = *(const float4*)(cw + c * 4);
  const float* p = proj + (size_t)bt * NPAD + II + c;
  float acc = cb[c];
  if (t >= 3) {
    acc += p[-3 * (ptrdiff_t)NPAD] * w.x + p[-2 * (ptrdiff_t)NPAD] * w.y
         + p[-(ptrdiff_t)NPAD] * w.z + p[0] * w.w;
  } else {
    const float* pw = &w.x;
    for (int k = 3 - t; k <= 3; ++k)
      acc += p[(ptrdiff_t)(k - 3) * NPAD] * pw[k];
  }
  xbc[(size_t)bt * CONVD + c] = acc / (1.f + __expf(-acc));
}

/* ---------------- dt_p = softplus(dt + bias), dA = exp(dt_p * A) -------- */
__global__ __launch_bounds__(256) void dt_kernel(const float* __restrict__ proj,
                                                 const float* __restrict__ dt_bias,
                                                 const float* __restrict__ A_log,
                                                 float* __restrict__ dtp,
                                                 float* __restrict__ dA) {
  const int idx = blockIdx.x * 256 + threadIdx.x;   /* < 262144 */
  const int bt = idx >> 6, h = idx & 63;
  const float z = proj[(size_t)bt * NPAD + (II + CONVD) + h] + dt_bias[h];
  const float sp = (z > 20.f) ? z : log1pf(__expf(z));
  const float a = -__expf(A_log[h]);
  dtp[idx] = sp;
  dA[idx] = __expf(sp * a);
}

/* ---------------- conv_state_new = hbc[:, L-3:, :] transposed ----------- */
__global__ __launch_bounds__(256) void convstate_kernel(const float* __restrict__ proj,
                                                        float* __restrict__ outp) {
  const int idx = blockIdx.x * 256 + threadIdx.x;
  if (idx >= BB * CONVD * 3) return;
  const int b = idx / (CONVD * 3);
  const int r = idx - b * CONVD * 3;
  const int c = r / 3, j = r - c * 3;
  outp[idx] = proj[((size_t)b * LL + (LL - 3 + j)) * NPAD + II + c];
}

/* ---------------- selective scan: one block per (b,h) ------------------- */
__device__ __forceinline__ void scan_issue(const float* row, const float* dtpP,
                                           const float* dAP, float* dstbuf,
                                           int wave, int lane, int h, int g) {
  for (int c = wave; c < 5; c += 4) {
    const int e = c * 64 + lane;
    int col;
    if (e < 64)       col = h * 64 + e;
    else if (e < 192) col = II + g * 128 + (e - 64);
    else              col = II + GN_ + g * 128 + (e - 192);
    gl2lds4(row + col, dstbuf + c * 64);
  }
  if (wave == 1 && lane < 2) {
    const float* p = (lane == 0) ? dtpP : dAP;
    gl2lds4(p, dstbuf + 320);
  }
}

__global__ __launch_bounds__(256) void scan_kernel(const float* __restrict__ xbc,
                                                   const float* __restrict__ dtp,
                                                   const float* __restrict__ dA,
                                                   const float* __restrict__ Dv,
                                                   float* __restrict__ y,
                                                   float* __restrict__ fst) {
  const int bh = blockIdx.x;            /* 0..127 */
  const int b = bh >> 6, h = bh & 63;
  const int g = h >> 3;
  const int tid = threadIdx.x;
  const int wave = tid >> 6, lane = tid & 63;
  const int pq = tid >> 4, nq = tid & 15;   /* p block (4), n block (8) */

  __shared__ __align__(16) float sbuf[2][324];

  const float* base  = xbc + (size_t)b * LL * CONVD;
  const float* dtpB  = dtp + (size_t)b * LL * HH + h;
  const float* dAB   = dA  + (size_t)b * LL * HH + h;
  const float  Dh    = Dv[h];

  float st[4][8];
#pragma unroll
  for (int i = 0; i < 4; ++i)
#pragma unroll
    for (int j = 0; j < 8; ++j) st[i][j] = 0.f;

  scan_issue(base, dtpB, dAB, &sbuf[0][0], wave, lane, h, g);
  __syncthreads();

  for (int t = 0; t < LL; ++t) {
    const int cur = t & 1;
    if (t + 1 < LL)
      scan_issue(base + (size_t)(t + 1) * CONVD, dtpB + (size_t)(t + 1) * HH,
                 dAB + (size_t)(t + 1) * HH, &sbuf[cur ^ 1][0], wave, lane, h, g);

    const float* sb = &sbuf[cur][0];
    const float dtpv = sb[320];
    const float da   = sb[321];
    const float4 xv = *(const float4*)(sb + pq * 4);
    const float4 b0 = *(const float4*)(sb + 64 + nq * 8);
    const float4 b1 = *(const float4*)(sb + 64 + nq * 8 + 4);
    const float4 c0 = *(const float4*)(sb + 192 + nq * 8);
    const float4 c1 = *(const float4*)(sb + 192 + nq * 8 + 4);
    const float* xp = (const float*)&xv;

    float acc[4];
#pragma unroll
    for (int i = 0; i < 4; ++i) {
      const float coef = dtpv * xp[i];
      float a = 0.f;
      st[i][0] = st[i][0] * da + coef * b0.x; a += st[i][0] * c0.x;
      st[i][1] = st[i][1] * da + coef * b0.y; a += st[i][1] * c0.y;
      st[i][2] = st[i][2] * da + coef * b0.z; a += st[i][2] * c0.z;
      st[i][3] = st[i][3] * da + coef * b0.w; a += st[i][3] * c0.w;
      st[i][4] = st[i][4] * da + coef * b1.x; a += st[i][4] * c1.x;
      st[i][5] = st[i][5] * da + coef * b1.y; a += st[i][5] * c1.y;
      st[i][6] = st[i][6] * da + coef * b1.z; a += st[i][6] * c1.z;
      st[i][7] = st[i][7] * da + coef * b1.w; a += st[i][7] * c1.w;
      acc[i] = a;
    }
#pragma unroll
    for (int m = 1; m <= 8; m <<= 1) {
#pragma unroll
      for (int i = 0; i < 4; ++i) acc[i] += __shfl_xor(acc[i], m);
    }
    if (nq == 0) {
      float4 o;
      o.x = acc[0] + Dh * xv.x;
      o.y = acc[1] + Dh * xv.y;
      o.z = acc[2] + Dh * xv.z;
      o.w = acc[3] + Dh * xv.w;
      *(float4*)(y + ((size_t)b * LL + t) * II + h * PP + pq * 4) = o;
    }
    __syncthreads();
  }

  /* final_state[b][h][p][n] */
#pragma unroll
  for (int i = 0; i < 4; ++i) {
    float* dst = fst + (((size_t)(b * HH + h) * PP) + pq * 4 + i) * NN + nq * 8;
    float4 v0 = { st[i][0], st[i][1], st[i][2], st[i][3] };
    float4 v1 = { st[i][4], st[i][5], st[i][6], st[i][7] };
    *(float4*)(dst)     = v0;
    *(float4*)(dst + 4) = v1;
  }
}

/* ---------------- groupnorm(512) * silu(gate) -> bf16 ------------------- */
__global__ __launch_bounds__(256) void norm_kernel(const float* __restrict__ y,
                                                   const float* __restrict__ proj,
                                                   const float* __restrict__ nw,
                                                   bf16* __restrict__ yn) {
  const int bt = blockIdx.x, tid = threadIdx.x;
  const float* yr = y + (size_t)bt * II + tid * 16;
  float4 v[4];
  float ss = 0.f;
#pragma unroll
  for (int i = 0; i < 4; ++i) {
    v[i] = *(const float4*)(yr + i * 4);
    ss += v[i].x * v[i].x + v[i].y * v[i].y + v[i].z * v[i].z + v[i].w * v[i].w;
  }
#pragma unroll
  for (int m = 1; m <= 16; m <<= 1) ss += __shfl_xor(ss, m);
  const float rstd = rsqrtf(ss * (1.f / 512.f) + 1e-5f);

  const float* gr  = proj + (size_t)bt * NPAD + tid * 16;
  const float* nwr = nw + tid * 16;
  bf16x8 o0, o1;
#pragma unroll
  for (int i = 0; i < 4; ++i) {
    float4 gv = *(const float4*)(gr + i * 4);
    float4 nv = *(const float4*)(nwr + i * 4);
    const float* vv = (const float*)&v[i];
    const float* gg = (const float*)&gv;
    const float* nn = (const float*)&nv;
#pragma unroll
    for (int j = 0; j < 4; ++j) {
      const float gate = gg[j];
      const float val = vv[j] * rstd * nn[j] * (gate / (1.f + __expf(-gate)));
      if (i < 2) o0[i * 4 + j] = (bf16)val;
      else       o1[(i - 2) * 4 + j] = (bf16)val;
    }
  }
  bf16* dst = yn + (size_t)bt * II + tid * 16;
  *(bf16x8*)(dst)     = o0;
  *(bf16x8*)(dst + 8) = o1;
}

extern "C" void kernel_launch(void* const* d_in, const int* in_sizes, int n_in,
                              void* d_out, int out_size, void* d_ws, size_t ws_size,
                              hipStream_t stream) {
  const float* hs      = (const float*)d_in[0];
  const float* w_in    = (const float*)d_in[1];
  const float* cw      = (const float*)d_in[2];
  const float* cb      = (const float*)d_in[3];
  const float* dt_bias = (const float*)d_in[4];
  const float* A_log   = (const float*)d_in[5];
  const float* Dv      = (const float*)d_in[6];
  const float* nw      = (const float*)d_in[7];
  const float* w_out   = (const float*)d_in[8];

  char* ws = (char*)d_ws;
  bf16*  hsb   = (bf16*)(ws + WS_HSB);
  bf16*  winb  = (bf16*)(ws + WS_WINB);
  float* proj  = (float*)(ws + WS_PROJ);
  float* xbc   = (float*)(ws + WS_XBC);
  float* dtp   = (float*)(ws + WS_DTP);
  float* dAb   = (float*)(ws + WS_DA);
  float* ybuf  = (float*)(ws + WS_Y);
  bf16*  ynb   = (bf16*)(ws + WS_YNB);
  bf16*  woutb = (bf16*)(ws + WS_WOUTB);

  float* outp = (float*)d_out;

  cast_kernel<<<16384, 256, 0, stream>>>(hs, hsb, 16777216L, 16777216L);
  cast_kernel<<<41472, 256, 0, stream>>>(w_in, winb, (long)PROJD * DM, (long)NPAD * DM);
  cast_kernel<<<16384, 256, 0, stream>>>(w_out, woutb, 16777216L, 16777216L);

  gemm_bt<<<dim3(NPAD / 128, BT / 128), 256, 0, stream>>>(hsb, winb, proj, BT, NPAD, DM);

  conv_kernel<<<dim3(CONVD / 256, BT), 256, 0, stream>>>(proj, cw, cb, xbc);
  dt_kernel<<<(BT * HH) / 256, 256, 0, stream>>>(proj, dt_bias, A_log, dtp, dAb);
  convstate_kernel<<<(BB * CONVD * 3 + 255) / 256, 256, 0, stream>>>(proj, outp + OUT_OFS_CONV);

  scan_kernel<<<BB * HH, 256, 0, stream>>>(xbc, dtp, dAb, Dv, ybuf, outp + OUT_OFS_STATE);

  norm_kernel<<<BT, 256, 0, stream>>>(ybuf, proj, nw, ynb);

  gemm_bt<<<dim3(DM / 128, BT / 128), 256, 0, stream>>>(ynb, woutb, outp, BT, DM, II);
}

// Round 2
// 2458.298 us; speedup vs baseline: 1.2197x; 1.2197x over previous
//
#include <hip/hip_runtime.h>
#include <cstdint>
#include <cstddef>

typedef __bf16 bf16;
typedef float f32x4 __attribute__((ext_vector_type(4)));
typedef bf16 bf16x8 __attribute__((ext_vector_type(8)));
typedef bf16 bf16x4 __attribute__((ext_vector_type(4)));

#define DM    4096
#define LL    2048
#define BB    2
#define BT    4096      /* B*L */
#define II    4096
#define GN_   1024
#define CONVD 6144
#define PROJD 10304
#define NPAD  10368     /* PROJ padded to multiple of 128 */
#define HH    64
#define PP    64
#define NN    128

/* ---- output layout (floats) ---- */
#define OUT_OFS_CONV  16777216   /* 4096*4096 */
#define OUT_OFS_STATE 16814080   /* + 2*6144*3 */

/* ---- workspace layout (bytes) ---- */
#define WS_HSB    0UL                   /* bf16 4096x4096      33554432 */
#define WS_WINB   33554432UL            /* bf16 10368x4096     84934656 */
#define WS_PROJ   118489088UL           /* f32  4096x10368    169869312 */
#define WS_XBC    288358400UL           /* f32  4096x6144     100663296 */
#define WS_DTDA   389021696UL           /* f32  4096x64x2       2097152 */
#define WS_Y      391118848UL           /* f32  4096x4096      67108864 */
#define WS_YNB    458227712UL           /* bf16 4096x4096      33554432 */
#define WS_WOUTB  491782144UL           /* bf16 4096x4096      33554432 */

__device__ __forceinline__ void gl2lds16(const void* g, void* l) {
  __builtin_amdgcn_global_load_lds(
      (__attribute__((address_space(1))) unsigned int*)(uintptr_t)g,
      (__attribute__((address_space(3))) unsigned int*)(uintptr_t)l, 16, 0, 0);
}

/* ---------------- cast fp32 -> bf16 (with zero-pad tail) ---------------- */
__global__ __launch_bounds__(256) void cast_kernel(const float* __restrict__ src,
                                                   bf16* __restrict__ dst,
                                                   long nsrc, long ndst) {
  long i = ((long)blockIdx.x * 256 + threadIdx.x) * 4;
  if (i >= ndst) return;
  bf16x4 o;
  if (i < nsrc) {
    float4 v = *(const float4*)(src + i);
    o[0] = (bf16)v.x; o[1] = (bf16)v.y; o[2] = (bf16)v.z; o[3] = (bf16)v.w;
  } else {
    o[0] = (bf16)0.f; o[1] = (bf16)0.f; o[2] = (bf16)0.f; o[3] = (bf16)0.f;
  }
  *(bf16x4*)(dst + i) = o;
}

/* ---------------- bf16 MFMA GEMM, C[M,N] = A[M,K] * B[N,K]^T ------------ */
__global__ __launch_bounds__(256, 3) void gemm_bt(const bf16* __restrict__ A,
                                                  const bf16* __restrict__ B,
                                                  float* __restrict__ C,
                                                  int M, int N, int K) {
  const int nb = blockIdx.x, mb = blockIdx.y;
  const int tid  = threadIdx.x;
  const int wave = tid >> 6, lane = tid & 63;
  const int wm = wave >> 1, wn = wave & 1;
  const int l16 = lane & 15, quad = lane >> 4;

  __shared__ __align__(16) bf16 As[128][32];
  __shared__ __align__(16) bf16 Bs[128][32];

  const int r0 = lane >> 2;
  const int kc = (lane & 3) * 8;
  const int c0 = wave * 2, c1 = wave * 2 + 1;
  const bf16* pA0 = A + (size_t)(mb * 128 + c0 * 16 + r0) * K + kc;
  const bf16* pA1 = A + (size_t)(mb * 128 + c1 * 16 + r0) * K + kc;
  const bf16* pB0 = B + (size_t)(nb * 128 + c0 * 16 + r0) * K + kc;
  const bf16* pB1 = B + (size_t)(nb * 128 + c1 * 16 + r0) * K + kc;
  bf16* lA0 = &As[c0 * 16][0]; bf16* lA1 = &As[c1 * 16][0];
  bf16* lB0 = &Bs[c0 * 16][0]; bf16* lB1 = &Bs[c1 * 16][0];

  f32x4 acc[4][4];
#pragma unroll
  for (int i = 0; i < 4; ++i)
#pragma unroll
    for (int j = 0; j < 4; ++j) acc[i][j] = (f32x4)0.f;

  for (int k0 = 0; k0 < K; k0 += 32) {
    gl2lds16(pA0, lA0); gl2lds16(pA1, lA1);
    gl2lds16(pB0, lB0); gl2lds16(pB1, lB1);
    pA0 += 32; pA1 += 32; pB0 += 32; pB1 += 32;
    __syncthreads();
    bf16x8 af[4], bfr[4];
#pragma unroll
    for (int mt = 0; mt < 4; ++mt)
      af[mt] = *(const bf16x8*)&As[wm * 64 + mt * 16 + l16][quad * 8];
#pragma unroll
    for (int nt = 0; nt < 4; ++nt)
      bfr[nt] = *(const bf16x8*)&Bs[wn * 64 + nt * 16 + l16][quad * 8];
#pragma unroll
    for (int mt = 0; mt < 4; ++mt)
#pragma unroll
      for (int nt = 0; nt < 4; ++nt)
        acc[mt][nt] = __builtin_amdgcn_mfma_f32_16x16x32_bf16(af[mt], bfr[nt], acc[mt][nt], 0, 0, 0);
    __syncthreads();
  }

#pragma unroll
  for (int mt = 0; mt < 4; ++mt) {
    const int row0 = mb * 128 + wm * 64 + mt * 16 + quad * 4;
#pragma unroll
    for (int nt = 0; nt < 4; ++nt) {
      const int col = nb * 128 + wn * 64 + nt * 16 + l16;
#pragma unroll
      for (int r = 0; r < 4; ++r)
        C[(size_t)(row0 + r) * N + col] = acc[mt][nt][r];
    }
  }
}

/* ---------------- conv(K=4) + SiLU over hbc slice ----------------------- */
__global__ __launch_bounds__(256) void conv_kernel(const float* __restrict__ proj,
                                                   const float* __restrict__ cw,
                                                   const float* __restrict__ cb,
                                                   float* __restrict__ xbc) {
  const int c  = blockIdx.x * 256 + threadIdx.x;
  const int bt = blockIdx.y;
  const int t  = bt & (LL - 1);
  const float4 w = *(const float4*)(cw + c * 4);
  const float* p = proj + (size_t)bt * NPAD + II + c;
  float acc = cb[c];
  if (t >= 3) {
    acc += p[-3 * (ptrdiff_t)NPAD] * w.x + p[-2 * (ptrdiff_t)NPAD] * w.y
         + p[-(ptrdiff_t)NPAD] * w.z + p[0] * w.w;
  } else {
    const float* pw = &w.x;
    for (int k = 3 - t; k <= 3; ++k)
      acc += p[(ptrdiff_t)(k - 3) * NPAD] * pw[k];
  }
  xbc[(size_t)bt * CONVD + c] = acc / (1.f + __expf(-acc));
}

/* -------- dtda[bt][h] = {softplus(dt+bias), exp(sp * -exp(A_log))} ------ */
__global__ __launch_bounds__(256) void dt_kernel(const float* __restrict__ proj,
                                                 const float* __restrict__ dt_bias,
                                                 const float* __restrict__ A_log,
                                                 float* __restrict__ dtda) {
  const int idx = blockIdx.x * 256 + threadIdx.x;   /* < 262144 */
  const int bt = idx >> 6, h = idx & 63;
  const float z = proj[(size_t)bt * NPAD + (II + CONVD) + h] + dt_bias[h];
  const float sp = (z > 20.f) ? z : log1pf(__expf(z));
  const float a = -__expf(A_log[h]);
  float2 o; o.x = sp; o.y = __expf(sp * a);
  *(float2*)(dtda + (size_t)idx * 2) = o;
}

/* ---------------- conv_state_new = hbc[:, L-3:, :] transposed ----------- */
__global__ __launch_bounds__(256) void convstate_kernel(const float* __restrict__ proj,
                                                        float* __restrict__ outp) {
  const int idx = blockIdx.x * 256 + threadIdx.x;
  if (idx >= BB * CONVD * 3) return;
  const int b = idx / (CONVD * 3);
  const int r = idx - b * CONVD * 3;
  const int c = r / 3, j = r - c * 3;
  outp[idx] = proj[((size_t)b * LL + (LL - 3 + j)) * NPAD + II + c];
}

/* ---------------- selective scan: register-pipelined, no LDS ------------ */
/* grid 256 = (b, h, p-half); block 128 = 8 pq x 16 nq; state 4p x 8n/thr.  */
#define SDEPTH 8
__global__ __launch_bounds__(128) void scan_kernel(const float* __restrict__ xbc,
                                                   const float* __restrict__ dtda,
                                                   const float* __restrict__ Dv,
                                                   float* __restrict__ y,
                                                   float* __restrict__ fst) {
  const int blk = blockIdx.x;           /* 0..255 */
  const int b  = blk >> 7;
  const int h  = (blk >> 1) & 63;
  const int ph = blk & 1;
  const int g  = h >> 3;
  const int tid = threadIdx.x;
  const int pq = tid >> 4;              /* 0..7  */
  const int nq = tid & 15;              /* 0..15 */

  const float Dh = Dv[h];

  const float* px = xbc + (size_t)b * LL * CONVD + h * 64 + ph * 32 + pq * 4;
  const float* pb = xbc + (size_t)b * LL * CONVD + II + g * 128 + nq * 8;
  const float* pc = xbc + (size_t)b * LL * CONVD + II + GN_ + g * 128 + nq * 8;
  const float* pd = dtda + (size_t)b * LL * 128 + h * 2;
  float*       py = y + (size_t)b * LL * II + h * 64 + ph * 32 + pq * 4;

  float st[4][8];
#pragma unroll
  for (int i = 0; i < 4; ++i)
#pragma unroll
    for (int j = 0; j < 8; ++j) st[i][j] = 0.f;

  float4 bx[SDEPTH], bb0[SDEPTH], bb1[SDEPTH], bc0[SDEPTH], bc1[SDEPTH];
  float2 bd[SDEPTH];

  /* prologue: t = 0..SDEPTH-1 (overreads past region end stay inside ws)  */
#pragma unroll
  for (int j = 0; j < SDEPTH; ++j) {
    bx[j]  = *(const float4*)(px + (size_t)j * CONVD);
    bb0[j] = *(const float4*)(pb + (size_t)j * CONVD);
    bb1[j] = *(const float4*)(pb + (size_t)j * CONVD + 4);
    bc0[j] = *(const float4*)(pc + (size_t)j * CONVD);
    bc1[j] = *(const float4*)(pc + (size_t)j * CONVD + 4);
    bd[j]  = *(const float2*)(pd + (size_t)j * 128);
  }

  for (int t = 0; t < LL; t += SDEPTH) {
#pragma unroll
    for (int j = 0; j < SDEPTH; ++j) {
      const float4 xv = bx[j];
      const float4 b0 = bb0[j], b1 = bb1[j];
      const float4 c0 = bc0[j], c1 = bc1[j];
      const float2 dd = bd[j];

      /* issue prefetch for t+j+SDEPTH (unconditional; tail reads are into
         mapped ws regions and never consumed) */
      const size_t tn = (size_t)(t + j + SDEPTH);
      bx[j]  = *(const float4*)(px + tn * CONVD);
      bb0[j] = *(const float4*)(pb + tn * CONVD);
      bb1[j] = *(const float4*)(pb + tn * CONVD + 4);
      bc0[j] = *(const float4*)(pc + tn * CONVD);
      bc1[j] = *(const float4*)(pc + tn * CONVD + 4);
      bd[j]  = *(const float2*)(pd + tn * 128);

      const float dtpv = dd.x, da = dd.y;
      const float* xp = (const float*)&xv;
      float acc[4];
#pragma unroll
      for (int i = 0; i < 4; ++i) {
        const float coef = dtpv * xp[i];
        float a = 0.f;
        st[i][0] = st[i][0] * da + coef * b0.x; a += st[i][0] * c0.x;
        st[i][1] = st[i][1] * da + coef * b0.y; a += st[i][1] * c0.y;
        st[i][2] = st[i][2] * da + coef * b0.z; a += st[i][2] * c0.z;
        st[i][3] = st[i][3] * da + coef * b0.w; a += st[i][3] * c0.w;
        st[i][4] = st[i][4] * da + coef * b1.x; a += st[i][4] * c1.x;
        st[i][5] = st[i][5] * da + coef * b1.y; a += st[i][5] * c1.y;
        st[i][6] = st[i][6] * da + coef * b1.z; a += st[i][6] * c1.z;
        st[i][7] = st[i][7] * da + coef * b1.w; a += st[i][7] * c1.w;
        acc[i] = a;
      }
#pragma unroll
      for (int m = 1; m <= 8; m <<= 1) {
#pragma unroll
        for (int i = 0; i < 4; ++i) acc[i] += __shfl_xor(acc[i], m);
      }
      if (nq == 0) {
        float4 o;
        o.x = acc[0] + Dh * xv.x;
        o.y = acc[1] + Dh * xv.y;
        o.z = acc[2] + Dh * xv.z;
        o.w = acc[3] + Dh * xv.w;
        *(float4*)(py + (size_t)(t + j) * II) = o;
      }
    }
  }

  /* final_state[b][h][p][n], p = ph*32 + pq*4 + i */
#pragma unroll
  for (int i = 0; i < 4; ++i) {
    float* dst = fst + (((size_t)(b * HH + h) * PP) + ph * 32 + pq * 4 + i) * NN + nq * 8;
    float4 v0 = { st[i][0], st[i][1], st[i][2], st[i][3] };
    float4 v1 = { st[i][4], st[i][5], st[i][6], st[i][7] };
    *(float4*)(dst)     = v0;
    *(float4*)(dst + 4) = v1;
  }
}

/* ---------------- groupnorm(512) * silu(gate) -> bf16 ------------------- */
__global__ __launch_bounds__(256) void norm_kernel(const float* __restrict__ y,
                                                   const float* __restrict__ proj,
                                                   const float* __restrict__ nw,
                                                   bf16* __restrict__ yn) {
  const int bt = blockIdx.x, tid = threadIdx.x;
  const float* yr = y + (size_t)bt * II + tid * 16;
  float4 v[4];
  float ss = 0.f;
#pragma unroll
  for (int i = 0; i < 4; ++i) {
    v[i] = *(const float4*)(yr + i * 4);
    ss += v[i].x * v[i].x + v[i].y * v[i].y + v[i].z * v[i].z + v[i].w * v[i].w;
  }
#pragma unroll
  for (int m = 1; m <= 16; m <<= 1) ss += __shfl_xor(ss, m);
  const float rstd = rsqrtf(ss * (1.f / 512.f) + 1e-5f);

  const float* gr  = proj + (size_t)bt * NPAD + tid * 16;
  const float* nwr = nw + tid * 16;
  bf16x8 o0, o1;
#pragma unroll
  for (int i = 0; i < 4; ++i) {
    float4 gv = *(const float4*)(gr + i * 4);
    float4 nv = *(const float4*)(nwr + i * 4);
    const float* vv = (const float*)&v[i];
    const float* gg = (const float*)&gv;
    const float* nn = (const float*)&nv;
#pragma unroll
    for (int j = 0; j < 4; ++j) {
      const float gate = gg[j];
      const float val = vv[j] * rstd * nn[j] * (gate / (1.f + __expf(-gate)));
      if (i < 2) o0[i * 4 + j] = (bf16)val;
      else       o1[(i - 2) * 4 + j] = (bf16)val;
    }
  }
  bf16* dst = yn + (size_t)bt * II + tid * 16;
  *(bf16x8*)(dst)     = o0;
  *(bf16x8*)(dst + 8) = o1;
}

extern "C" void kernel_launch(void* const* d_in, const int* in_sizes, int n_in,
                              void* d_out, int out_size, void* d_ws, size_t ws_size,
                              hipStream_t stream) {
  const float* hs      = (const float*)d_in[0];
  const float* w_in    = (const float*)d_in[1];
  const float* cw      = (const float*)d_in[2];
  const float* cb      = (const float*)d_in[3];
  const float* dt_bias = (const float*)d_in[4];
  const float* A_log   = (const float*)d_in[5];
  const float* Dv      = (const float*)d_in[6];
  const float* nw      = (const float*)d_in[7];
  const float* w_out   = (const float*)d_in[8];

  char* ws = (char*)d_ws;
  bf16*  hsb   = (bf16*)(ws + WS_HSB);
  bf16*  winb  = (bf16*)(ws + WS_WINB);
  float* proj  = (float*)(ws + WS_PROJ);
  float* xbc   = (float*)(ws + WS_XBC);
  float* dtda  = (float*)(ws + WS_DTDA);
  float* ybuf  = (float*)(ws + WS_Y);
  bf16*  ynb   = (bf16*)(ws + WS_YNB);
  bf16*  woutb = (bf16*)(ws + WS_WOUTB);

  float* outp = (float*)d_out;

  cast_kernel<<<16384, 256, 0, stream>>>(hs, hsb, 16777216L, 16777216L);
  cast_kernel<<<41472, 256, 0, stream>>>(w_in, winb, (long)PROJD * DM, (long)NPAD * DM);
  cast_kernel<<<16384, 256, 0, stream>>>(w_out, woutb, 16777216L, 16777216L);

  gemm_bt<<<dim3(NPAD / 128, BT / 128), 256, 0, stream>>>(hsb, winb, proj, BT, NPAD, DM);

  conv_kernel<<<dim3(CONVD / 256, BT), 256, 0, stream>>>(proj, cw, cb, xbc);
  dt_kernel<<<(BT * HH) / 256, 256, 0, stream>>>(proj, dt_bias, A_log, dtda);
  convstate_kernel<<<(BB * CONVD * 3 + 255) / 256, 256, 0, stream>>>(proj, outp + OUT_OFS_CONV);

  scan_kernel<<<BB * HH * 2, 128, 0, stream>>>(xbc, dtda, Dv, ybuf, outp + OUT_OFS_STATE);

  norm_kernel<<<BT, 256, 0, stream>>>(ybuf, proj, nw, ynb);

  gemm_bt<<<dim3(DM / 128, BT / 128), 256, 0, stream>>>(ynb, woutb, outp, BT, DM, II);
}

// Round 3
// 1408.759 us; speedup vs baseline: 2.1284x; 1.7450x over previous
//
#include <hip/hip_runtime.h>
#include <cstdint>
#include <cstddef>

typedef __bf16 bf16;
typedef float f32x4 __attribute__((ext_vector_type(4)));
typedef bf16 bf16x8 __attribute__((ext_vector_type(8)));
typedef bf16 bf16x4 __attribute__((ext_vector_type(4)));

#define DM    4096
#define LL    2048
#define BB    2
#define BT    4096      /* B*L */
#define II    4096
#define GN_   1024
#define CONVD 6144
#define PROJD 10304
#define NPAD  10368
#define HH    64
#define PP    64
#define NN    128
#define CT    64        /* chunk length */
#define NC    32        /* chunks per sequence */

/* ---- output layout (floats) ---- */
#define OUT_OFS_CONV  16777216
#define OUT_OFS_STATE 16814080

/* ---- workspace layout (bytes) ---- */
#define WS_DSB    0UL                   /* bf16 [b][h][c][64][128]  67108864 (overlaps hsb/winb, dead after gemm1) */
#define WS_HSB    0UL                   /* bf16 4096x4096      33554432 */
#define WS_WINB   33554432UL            /* bf16 10368x4096     84934656 */
#define WS_PROJ   118489088UL           /* f32  4096x10368    169869312 */
#define WS_XBC    288358400UL           /* f32  4096x6144     100663296 */
#define WS_DTDA   389021696UL           /* f32  4096x64x2       2097152 */
#define WS_Y      391118848UL           /* f32  4096x4096      67108864 */
#define WS_YNB    458227712UL           /* bf16 4096x4096      33554432 */
#define WS_WOUTB  491782144UL           /* bf16 4096x4096      33554432 */

__device__ __forceinline__ void gl2lds16(const void* g, void* l) {
  __builtin_amdgcn_global_load_lds(
      (__attribute__((address_space(1))) unsigned int*)(uintptr_t)g,
      (__attribute__((address_space(3))) unsigned int*)(uintptr_t)l, 16, 0, 0);
}

/* ---------------- cast fp32 -> bf16 (with zero-pad tail) ---------------- */
__global__ __launch_bounds__(256) void cast_kernel(const float* __restrict__ src,
                                                   bf16* __restrict__ dst,
                                                   long nsrc, long ndst) {
  long i = ((long)blockIdx.x * 256 + threadIdx.x) * 4;
  if (i >= ndst) return;
  bf16x4 o;
  if (i < nsrc) {
    float4 v = *(const float4*)(src + i);
    o[0] = (bf16)v.x; o[1] = (bf16)v.y; o[2] = (bf16)v.z; o[3] = (bf16)v.w;
  } else {
    o[0] = (bf16)0.f; o[1] = (bf16)0.f; o[2] = (bf16)0.f; o[3] = (bf16)0.f;
  }
  *(bf16x4*)(dst + i) = o;
}

/* ---------------- bf16 MFMA GEMM, C[M,N] = A[M,K] * B[N,K]^T ------------ */
__global__ __launch_bounds__(256, 3) void gemm_bt(const bf16* __restrict__ A,
                                                  const bf16* __restrict__ B,
                                                  float* __restrict__ C,
                                                  int M, int N, int K) {
  const int nb = blockIdx.x, mb = blockIdx.y;
  const int tid  = threadIdx.x;
  const int wave = tid >> 6, lane = tid & 63;
  const int wm = wave >> 1, wn = wave & 1;
  const int l16 = lane & 15, quad = lane >> 4;

  __shared__ __align__(16) bf16 As[128][32];
  __shared__ __align__(16) bf16 Bs[128][32];

  const int r0 = lane >> 2;
  const int kc = (lane & 3) * 8;
  const int c0 = wave * 2, c1 = wave * 2 + 1;
  const bf16* pA0 = A + (size_t)(mb * 128 + c0 * 16 + r0) * K + kc;
  const bf16* pA1 = A + (size_t)(mb * 128 + c1 * 16 + r0) * K + kc;
  const bf16* pB0 = B + (size_t)(nb * 128 + c0 * 16 + r0) * K + kc;
  const bf16* pB1 = B + (size_t)(nb * 128 + c1 * 16 + r0) * K + kc;
  bf16* lA0 = &As[c0 * 16][0]; bf16* lA1 = &As[c1 * 16][0];
  bf16* lB0 = &Bs[c0 * 16][0]; bf16* lB1 = &Bs[c1 * 16][0];

  f32x4 acc[4][4];
#pragma unroll
  for (int i = 0; i < 4; ++i)
#pragma unroll
    for (int j = 0; j < 4; ++j) acc[i][j] = (f32x4)0.f;

  for (int k0 = 0; k0 < K; k0 += 32) {
    gl2lds16(pA0, lA0); gl2lds16(pA1, lA1);
    gl2lds16(pB0, lB0); gl2lds16(pB1, lB1);
    pA0 += 32; pA1 += 32; pB0 += 32; pB1 += 32;
    __syncthreads();
    bf16x8 af[4], bfr[4];
#pragma unroll
    for (int mt = 0; mt < 4; ++mt)
      af[mt] = *(const bf16x8*)&As[wm * 64 + mt * 16 + l16][quad * 8];
#pragma unroll
    for (int nt = 0; nt < 4; ++nt)
      bfr[nt] = *(const bf16x8*)&Bs[wn * 64 + nt * 16 + l16][quad * 8];
#pragma unroll
    for (int mt = 0; mt < 4; ++mt)
#pragma unroll
      for (int nt = 0; nt < 4; ++nt)
        acc[mt][nt] = __builtin_amdgcn_mfma_f32_16x16x32_bf16(af[mt], bfr[nt], acc[mt][nt], 0, 0, 0);
    __syncthreads();
  }

#pragma unroll
  for (int mt = 0; mt < 4; ++mt) {
    const int row0 = mb * 128 + wm * 64 + mt * 16 + quad * 4;
#pragma unroll
    for (int nt = 0; nt < 4; ++nt) {
      const int col = nb * 128 + wn * 64 + nt * 16 + l16;
#pragma unroll
      for (int r = 0; r < 4; ++r)
        C[(size_t)(row0 + r) * N + col] = acc[mt][nt][r];
    }
  }
}

/* ---------------- conv(K=4) + SiLU over hbc slice ----------------------- */
__global__ __launch_bounds__(256) void conv_kernel(const float* __restrict__ proj,
                                                   const float* __restrict__ cw,
                                                   const float* __restrict__ cb,
                                                   float* __restrict__ xbc) {
  const int c  = blockIdx.x * 256 + threadIdx.x;
  const int bt = blockIdx.y;
  const int t  = bt & (LL - 1);
  const float4 w = *(const float4*)(cw + c * 4);
  const float* p = proj + (size_t)bt * NPAD + II + c;
  float acc = cb[c];
  if (t >= 3) {
    acc += p[-3 * (ptrdiff_t)NPAD] * w.x + p[-2 * (ptrdiff_t)NPAD] * w.y
         + p[-(ptrdiff_t)NPAD] * w.z + p[0] * w.w;
  } else {
    const float* pw = &w.x;
    for (int k = 3 - t; k <= 3; ++k)
      acc += p[(ptrdiff_t)(k - 3) * NPAD] * pw[k];
  }
  xbc[(size_t)bt * CONVD + c] = acc / (1.f + __expf(-acc));
}

/* -------- dtda[bt][h] = {softplus(dt+bias), exp(sp * -exp(A_log))} ------ */
__global__ __launch_bounds__(256) void dt_kernel(const float* __restrict__ proj,
                                                 const float* __restrict__ dt_bias,
                                                 const float* __restrict__ A_log,
                                                 float* __restrict__ dtda) {
  const int idx = blockIdx.x * 256 + threadIdx.x;
  const int bt = idx >> 6, h = idx & 63;
  const float z = proj[(size_t)bt * NPAD + (II + CONVD) + h] + dt_bias[h];
  const float sp = (z > 20.f) ? z : log1pf(__expf(z));
  const float a = -__expf(A_log[h]);
  float2 o; o.x = sp; o.y = __expf(sp * a);
  *(float2*)(dtda + (size_t)idx * 2) = o;
}

/* ---------------- conv_state_new = hbc[:, L-3:, :] transposed ----------- */
__global__ __launch_bounds__(256) void convstate_kernel(const float* __restrict__ proj,
                                                        float* __restrict__ outp) {
  const int idx = blockIdx.x * 256 + threadIdx.x;
  if (idx >= BB * CONVD * 3) return;
  const int b = idx / (CONVD * 3);
  const int r = idx - b * CONVD * 3;
  const int c = r / 3, j = r - c * 3;
  outp[idx] = proj[((size_t)b * LL + (LL - 3 + j)) * NPAD + II + c];
}

/* =============== chunked SSD scan =============== */
/* chunkA: per (b,h,c): G=C·B^T, W=mask(G), Yintra=W·X, dS=(wX)^T·B        */
__global__ __launch_bounds__(256) void chunkA_kernel(const float* __restrict__ xbc,
                                                     const float* __restrict__ dtda,
                                                     const float* __restrict__ A_log,
                                                     float* __restrict__ ybuf,
                                                     bf16* __restrict__ dsb) {
  const int h = blockIdx.x, c = blockIdx.y, b = blockIdx.z;
  const int g = h >> 3;
  const int tid = threadIdx.x;
  const int wave = tid >> 6, lane = tid & 63;
  const int l16 = lane & 15, quad = lane >> 4;

  /* CsBt: Cs[64][128] in phase1-2a, reused as Bt[128][64] in phase2b-3 */
  __shared__ __align__(16) bf16 CsBt[8192];
  __shared__ __align__(16) bf16 Bs[64][128];
  __shared__ __align__(16) bf16 Xt[64][64];
  __shared__ __align__(16) bf16 Ws[64][64];
  __shared__ float cums[64], dtps[64], wls[64];

  bf16 (*Cs)[128] = (bf16(*)[128])CsBt;
  bf16 (*Bt)[64]  = (bf16(*)[64])CsBt;

  const size_t rowbase = ((size_t)b * LL + (size_t)c * CT) * CONVD;

  /* ---- phase 1: stage Cs, Bs (swizzled), Xt (transposed) + cum scan ---- */
  {
    const int i = tid >> 2, col0 = (tid & 3) * 32;
    const float* gpC = xbc + rowbase + (size_t)i * CONVD + (II + GN_) + g * 128 + col0;
    const float* gpB = xbc + rowbase + (size_t)i * CONVD + II + g * 128 + col0;
    const int sx = i & 15;
#pragma unroll
    for (int k = 0; k < 8; ++k) {
      const int n = col0 + k * 4;
      const int eo = (((n >> 3) ^ sx) * 8) + (n & 7);
      float4 v = *(const float4*)(gpC + k * 4);
      bf16x4 o; o[0]=(bf16)v.x; o[1]=(bf16)v.y; o[2]=(bf16)v.z; o[3]=(bf16)v.w;
      *(bf16x4*)(&Cs[i][0] + eo) = o;
      float4 u = *(const float4*)(gpB + k * 4);
      bf16x4 p; p[0]=(bf16)u.x; p[1]=(bf16)u.y; p[2]=(bf16)u.z; p[3]=(bf16)u.w;
      *(bf16x4*)(&Bs[i][0] + eo) = p;
    }
  }
  {
    const int j = tid >> 2, p0 = (tid & 3) * 16;
    const float* gpX = xbc + rowbase + (size_t)j * CONVD + h * 64 + p0;
#pragma unroll
    for (int k = 0; k < 4; ++k) {
      float4 v = *(const float4*)(gpX + k * 4);
      const float* vv = (const float*)&v;
#pragma unroll
      for (int e = 0; e < 4; ++e) {
        const int pp = p0 + k * 4 + e;
        Xt[pp][(((j >> 3) ^ (pp & 7)) * 8) + (j & 7)] = (bf16)vv[e];
      }
    }
  }
  if (wave == 0) {
    const float Ah = -__expf(A_log[h]);
    float2 dd = *(const float2*)(dtda + ((size_t)((b * LL + c * CT + lane)) * 64 + h) * 2);
    float s = dd.x * Ah;
#pragma unroll
    for (int d = 1; d < 64; d <<= 1) {
      float v = __shfl_up(s, d);
      if (lane >= d) s += v;
    }
    const float tot = __shfl(s, 63);
    cums[lane] = s;
    dtps[lane] = dd.x;
    wls[lane]  = __expf(tot - s) * dd.x;
  }
  __syncthreads();

  /* ---- phase 2a: G = C·B^T, mask -> Ws ---- */
  const int mrow = wave * 16 + l16;
  {
    f32x4 accg[4];
#pragma unroll
    for (int nt = 0; nt < 4; ++nt) accg[nt] = (f32x4)0.f;
#pragma unroll
    for (int k0 = 0; k0 < 128; k0 += 32) {
      bf16x8 af = *(const bf16x8*)&Cs[mrow][(((k0 >> 3) + quad) ^ (mrow & 15)) * 8];
#pragma unroll
      for (int nt = 0; nt < 4; ++nt) {
        const int nrow = nt * 16 + l16;
        bf16x8 bfr = *(const bf16x8*)&Bs[nrow][(((k0 >> 3) + quad) ^ (nrow & 15)) * 8];
        accg[nt] = __builtin_amdgcn_mfma_f32_16x16x32_bf16(af, bfr, accg[nt], 0, 0, 0);
      }
    }
#pragma unroll
    for (int nt = 0; nt < 4; ++nt) {
      const int j = nt * 16 + l16;
#pragma unroll
      for (int r = 0; r < 4; ++r) {
        const int i = wave * 16 + quad * 4 + r;
        float v = 0.f;
        if (j <= i) v = accg[nt][r] * __expf(cums[i] - cums[j]) * dtps[j];
        Ws[i][(((j >> 3) ^ (i & 7)) * 8) + (j & 7)] = (bf16)v;
      }
    }
  }
  __syncthreads();   /* all Cs reads done; CsBt may be reused as Bt */

  /* ---- phase 2b: Bt[n][j] = Bs[j][n] (plain transpose) ---- */
  {
    const int n = tid >> 1, j0 = (tid & 1) * 32;
#pragma unroll
    for (int jj = 0; jj < 32; ++jj) {
      const int j = j0 + jj;
      bf16 v = Bs[j][(((n >> 3) ^ (j & 15)) * 8) + (n & 7)];
      Bt[n][(((j >> 3) ^ (n & 7)) * 8) + (j & 7)] = v;
    }
  }
  __syncthreads();

  /* ---- phase 3: Yintra = Ws·Xt^T ; dS = (w·X)^T·Bt^T ---- */
  f32x4 accy[4];
#pragma unroll
  for (int pt = 0; pt < 4; ++pt) accy[pt] = (f32x4)0.f;
#pragma unroll
  for (int k0 = 0; k0 < 64; k0 += 32) {
    bf16x8 af = *(const bf16x8*)&Ws[mrow][(((k0 >> 3) + quad) ^ (mrow & 7)) * 8];
#pragma unroll
    for (int pt = 0; pt < 4; ++pt) {
      const int prow = pt * 16 + l16;
      bf16x8 bfr = *(const bf16x8*)&Xt[prow][(((k0 >> 3) + quad) ^ (prow & 7)) * 8];
      accy[pt] = __builtin_amdgcn_mfma_f32_16x16x32_bf16(af, bfr, accy[pt], 0, 0, 0);
    }
  }

  f32x4 accs[8];
#pragma unroll
  for (int nt = 0; nt < 8; ++nt) accs[nt] = (f32x4)0.f;
#pragma unroll
  for (int k0 = 0; k0 < 64; k0 += 32) {
    bf16x8 axr = *(const bf16x8*)&Xt[mrow][(((k0 >> 3) + quad) ^ (mrow & 7)) * 8];
    bf16x8 ax;
#pragma unroll
    for (int e = 0; e < 8; ++e)
      ax[e] = (bf16)((float)axr[e] * wls[k0 + quad * 8 + e]);
#pragma unroll
    for (int nt = 0; nt < 8; ++nt) {
      const int nrow = nt * 16 + l16;
      bf16x8 bfr = *(const bf16x8*)&Bt[nrow][(((k0 >> 3) + quad) ^ (nrow & 7)) * 8];
      accs[nt] = __builtin_amdgcn_mfma_f32_16x16x32_bf16(ax, bfr, accs[nt], 0, 0, 0);
    }
  }

  /* ---- epilogue ---- */
#pragma unroll
  for (int pt = 0; pt < 4; ++pt) {
#pragma unroll
    for (int r = 0; r < 4; ++r) {
      const int i = wave * 16 + quad * 4 + r;
      ybuf[((size_t)(b * LL + c * CT + i)) * II + h * 64 + pt * 16 + l16] = accy[pt][r];
    }
  }
  const size_t dbase = (((size_t)(b * HH + h)) * NC + c) * (CT * NN);
#pragma unroll
  for (int nt = 0; nt < 8; ++nt) {
#pragma unroll
    for (int r = 0; r < 4; ++r) {
      const int p = wave * 16 + quad * 4 + r;
      dsb[dbase + (size_t)p * NN + nt * 16 + l16] = (bf16)accs[nt][r];
    }
  }
}

/* chain: serial over 32 chunks; in-place dS -> S_prev; final_state -> out */
__global__ __launch_bounds__(256) void chain_kernel(const float* __restrict__ dtda,
                                                    const float* __restrict__ A_log,
                                                    bf16* __restrict__ dsb,
                                                    float* __restrict__ fst) {
  const int blk = blockIdx.x;           /* b*128 + h*2 + half */
  const int b = blk >> 7, h = (blk >> 1) & 63, half = blk & 1;
  const int tid = threadIdx.x, wave = tid >> 6, lane = tid & 63;
  __shared__ float DcL[NC];

  const float Ah = -__expf(A_log[h]);
#pragma unroll
  for (int cc = 0; cc < 8; ++cc) {
    const int c = wave * 8 + cc;
    float2 dd = *(const float2*)(dtda + ((size_t)(b * LL + c * CT + lane) * 64 + h) * 2);
    float a = dd.x * Ah;
#pragma unroll
    for (int m = 1; m <= 32; m <<= 1) a += __shfl_xor(a, m);
    if (lane == 0) DcL[c] = __expf(a);
  }
  __syncthreads();

  const int local = half * 4096 + tid * 16;
  const size_t base = ((size_t)(b * HH + h)) * NC * (CT * NN) + local;
  float s[16];
#pragma unroll
  for (int e = 0; e < 16; ++e) s[e] = 0.f;

  for (int c = 0; c < NC; ++c) {
    bf16* p = dsb + base + (size_t)c * (CT * NN);
    bf16x8 d0 = *(const bf16x8*)(p);
    bf16x8 d1 = *(const bf16x8*)(p + 8);
    const float dc = DcL[c];
    bf16x8 o0, o1;
#pragma unroll
    for (int e = 0; e < 8; ++e) { o0[e] = (bf16)s[e]; o1[e] = (bf16)s[8 + e]; }
    *(bf16x8*)(p)     = o0;
    *(bf16x8*)(p + 8) = o1;
#pragma unroll
    for (int e = 0; e < 8; ++e) {
      s[e]     = s[e] * dc + (float)d0[e];
      s[8 + e] = s[8 + e] * dc + (float)d1[e];
    }
  }
  float* fp = fst + ((size_t)(b * HH + h)) * (PP * NN) + local;
#pragma unroll
  for (int k = 0; k < 4; ++k) {
    float4 v = { s[k * 4], s[k * 4 + 1], s[k * 4 + 2], s[k * 4 + 3] };
    *(float4*)(fp + k * 4) = v;
  }
}

/* chunkB: y = Yintra + exp(cum_i)*(C·S_prev^T) + D*x */
__global__ __launch_bounds__(256) void chunkB_kernel(const float* __restrict__ xbc,
                                                     const float* __restrict__ dtda,
                                                     const float* __restrict__ A_log,
                                                     const float* __restrict__ Dv,
                                                     const bf16* __restrict__ spb,
                                                     float* __restrict__ ybuf) {
  const int h = blockIdx.x, c = blockIdx.y, b = blockIdx.z;
  const int g = h >> 3;
  const int tid = threadIdx.x;
  const int wave = tid >> 6, lane = tid & 63;
  const int l16 = lane & 15, quad = lane >> 4;

  __shared__ __align__(16) bf16 Cs[64][128];
  __shared__ __align__(16) bf16 Sp[64][128];
  __shared__ float es[64];

  const size_t rowbase = ((size_t)b * LL + (size_t)c * CT) * CONVD;
  {
    const int i = tid >> 2, col0 = (tid & 3) * 32;
    const float* gpC = xbc + rowbase + (size_t)i * CONVD + (II + GN_) + g * 128 + col0;
    const int sx = i & 15;
#pragma unroll
    for (int k = 0; k < 8; ++k) {
      const int n = col0 + k * 4;
      float4 v = *(const float4*)(gpC + k * 4);
      bf16x4 o; o[0]=(bf16)v.x; o[1]=(bf16)v.y; o[2]=(bf16)v.z; o[3]=(bf16)v.w;
      *(bf16x4*)(&Cs[i][0] + (((n >> 3) ^ sx) * 8) + (n & 7)) = o;
    }
  }
  {
    const int p = tid >> 2, nseg = (tid & 3) * 32;
    const bf16* gp = spb + (((size_t)(b * HH + h)) * NC + c) * (CT * NN) + (size_t)p * NN + nseg;
    const int sx = p & 15;
#pragma unroll
    for (int k = 0; k < 4; ++k) {
      const int n0 = nseg + k * 8;
      bf16x8 v = *(const bf16x8*)(gp + k * 8);
      *(bf16x8*)(&Sp[p][0] + (((n0 >> 3) ^ sx) * 8)) = v;
    }
  }
  if (wave == 0) {
    const float Ah = -__expf(A_log[h]);
    float2 dd = *(const float2*)(dtda + ((size_t)(b * LL + c * CT + lane) * 64 + h) * 2);
    float s = dd.x * Ah;
#pragma unroll
    for (int d = 1; d < 64; d <<= 1) {
      float v = __shfl_up(s, d);
      if (lane >= d) s += v;
    }
    es[lane] = __expf(s);
  }
  __syncthreads();

  const int mrow = wave * 16 + l16;
  f32x4 acc[4];
#pragma unroll
  for (int pt = 0; pt < 4; ++pt) acc[pt] = (f32x4)0.f;
#pragma unroll
  for (int k0 = 0; k0 < 128; k0 += 32) {
    bf16x8 af = *(const bf16x8*)&Cs[mrow][(((k0 >> 3) + quad) ^ (mrow & 15)) * 8];
#pragma unroll
    for (int pt = 0; pt < 4; ++pt) {
      const int prow = pt * 16 + l16;
      bf16x8 bfr = *(const bf16x8*)&Sp[prow][(((k0 >> 3) + quad) ^ (prow & 15)) * 8];
      acc[pt] = __builtin_amdgcn_mfma_f32_16x16x32_bf16(af, bfr, acc[pt], 0, 0, 0);
    }
  }

  const float Dh = Dv[h];
#pragma unroll
  for (int pt = 0; pt < 4; ++pt) {
#pragma unroll
    for (int r = 0; r < 4; ++r) {
      const int i = wave * 16 + quad * 4 + r;
      const int p = pt * 16 + l16;
      const size_t row = (size_t)(b * LL + c * CT + i);
      const size_t ya = row * II + h * 64 + p;
      const float xv = xbc[row * CONVD + h * 64 + p];
      ybuf[ya] = acc[pt][r] * es[i] + ybuf[ya] + Dh * xv;
    }
  }
}

/* ---------------- groupnorm(512) * silu(gate) -> bf16 ------------------- */
__global__ __launch_bounds__(256) void norm_kernel(const float* __restrict__ y,
                                                   const float* __restrict__ proj,
                                                   const float* __restrict__ nw,
                                                   bf16* __restrict__ yn) {
  const int bt = blockIdx.x, tid = threadIdx.x;
  const float* yr = y + (size_t)bt * II + tid * 16;
  float4 v[4];
  float ss = 0.f;
#pragma unroll
  for (int i = 0; i < 4; ++i) {
    v[i] = *(const float4*)(yr + i * 4);
    ss += v[i].x * v[i].x + v[i].y * v[i].y + v[i].z * v[i].z + v[i].w * v[i].w;
  }
#pragma unroll
  for (int m = 1; m <= 16; m <<= 1) ss += __shfl_xor(ss, m);
  const float rstd = rsqrtf(ss * (1.f / 512.f) + 1e-5f);

  const float* gr  = proj + (size_t)bt * NPAD + tid * 16;
  const float* nwr = nw + tid * 16;
  bf16x8 o0, o1;
#pragma unroll
  for (int i = 0; i < 4; ++i) {
    float4 gv = *(const float4*)(gr + i * 4);
    float4 nv = *(const float4*)(nwr + i * 4);
    const float* vv = (const float*)&v[i];
    const float* gg = (const float*)&gv;
    const float* nn = (const float*)&nv;
#pragma unroll
    for (int j = 0; j < 4; ++j) {
      const float gate = gg[j];
      const float val = vv[j] * rstd * nn[j] * (gate / (1.f + __expf(-gate)));
      if (i < 2) o0[i * 4 + j] = (bf16)val;
      else       o1[(i - 2) * 4 + j] = (bf16)val;
    }
  }
  bf16* dst = yn + (size_t)bt * II + tid * 16;
  *(bf16x8*)(dst)     = o0;
  *(bf16x8*)(dst + 8) = o1;
}

extern "C" void kernel_launch(void* const* d_in, const int* in_sizes, int n_in,
                              void* d_out, int out_size, void* d_ws, size_t ws_size,
                              hipStream_t stream) {
  const float* hs      = (const float*)d_in[0];
  const float* w_in    = (const float*)d_in[1];
  const float* cw      = (const float*)d_in[2];
  const float* cb      = (const float*)d_in[3];
  const float* dt_bias = (const float*)d_in[4];
  const float* A_log   = (const float*)d_in[5];
  const float* Dv      = (const float*)d_in[6];
  const float* nw      = (const float*)d_in[7];
  const float* w_out   = (const float*)d_in[8];

  char* ws = (char*)d_ws;
  bf16*  hsb   = (bf16*)(ws + WS_HSB);
  bf16*  winb  = (bf16*)(ws + WS_WINB);
  bf16*  dsb   = (bf16*)(ws + WS_DSB);
  float* proj  = (float*)(ws + WS_PROJ);
  float* xbc   = (float*)(ws + WS_XBC);
  float* dtda  = (float*)(ws + WS_DTDA);
  float* ybuf  = (float*)(ws + WS_Y);
  bf16*  ynb   = (bf16*)(ws + WS_YNB);
  bf16*  woutb = (bf16*)(ws + WS_WOUTB);

  float* outp = (float*)d_out;

  cast_kernel<<<16384, 256, 0, stream>>>(hs, hsb, 16777216L, 16777216L);
  cast_kernel<<<41472, 256, 0, stream>>>(w_in, winb, (long)PROJD * DM, (long)NPAD * DM);
  cast_kernel<<<16384, 256, 0, stream>>>(w_out, woutb, 16777216L, 16777216L);

  gemm_bt<<<dim3(NPAD / 128, BT / 128), 256, 0, stream>>>(hsb, winb, proj, BT, NPAD, DM);

  conv_kernel<<<dim3(CONVD / 256, BT), 256, 0, stream>>>(proj, cw, cb, xbc);
  dt_kernel<<<(BT * HH) / 256, 256, 0, stream>>>(proj, dt_bias, A_log, dtda);
  convstate_kernel<<<(BB * CONVD * 3 + 255) / 256, 256, 0, stream>>>(proj, outp + OUT_OFS_CONV);

  chunkA_kernel<<<dim3(HH, NC, BB), 256, 0, stream>>>(xbc, dtda, A_log, ybuf, dsb);
  chain_kernel<<<BB * HH * 2, 256, 0, stream>>>(dtda, A_log, dsb, outp + OUT_OFS_STATE);
  chunkB_kernel<<<dim3(HH, NC, BB), 256, 0, stream>>>(xbc, dtda, A_log, Dv, dsb, ybuf);

  norm_kernel<<<BT, 256, 0, stream>>>(ybuf, proj, nw, ynb);

  gemm_bt<<<dim3(DM / 128, BT / 128), 256, 0, stream>>>(ynb, woutb, outp, BT, DM, II);
}